// Round 2
// baseline (492.395 us; speedup 1.0000x reference)
//
#include <hip/hip_runtime.h>
#include <math.h>

// Qwen3 MoE gate: logits = hidden @ W_gate^T ; softmax ; top-8 ; renorm.
// Outputs (flat float32 in d_out): sel_w [T*8], sel_idx-as-float [T*8], logits [T*64].
//
// Round 2 strategy: fp32 GEMM (compute-bound ~27us ideal) + top-9 gap check
// to flag tokens whose ordering could be perturbed by fp32 accumulation
// noise (~3.5e-6 std vs tau=2.5e-4 flag threshold vs ~0.066 mean gap), then
// fp64 re-dot + exact top-8 for the ~3% flagged tokens. Indices are the only
// output compared tightly (bf16-domain compare elsewhere), and fp64 ordering
// matched the np reference exactly in round 1.

#define HDIM 2048
#define NEXP 64
#define TOPK 8
#define NSCAN 9          // need 9th value for the rank-8/9 gap
#define TAU  2.5e-4f

// ---------------- Kernel A: fp32 GEMM, 32 tok x 64 exp per block ----------
// 128 threads: eg = tid&15 (experts eg+16j, j=0..3), tg = tid>>4 (0..7),
// tokens t*8+tg (t=0..3). LDS rows padded to 68 floats so compute-phase
// reads land on disjoint 4-bank groups (broadcast across duplicate lanes).
__global__ __launch_bounds__(128) void gate_gemm_f32(
    const float* __restrict__ hidden,   // [T, 2048]
    const float* __restrict__ wgate,    // [64, 2048]
    float* __restrict__ logits)         // [T, 64]
{
    __shared__ float Wt[NEXP][68];
    __shared__ float Hs[32][68];

    const int tid = threadIdx.x;
    const int eg  = tid & 15;
    const int tg  = tid >> 4;
    const size_t tokBase = (size_t)blockIdx.x * 32;

    float acc[4][4];
#pragma unroll
    for (int t = 0; t < 4; ++t)
#pragma unroll
        for (int j = 0; j < 4; ++j) acc[t][j] = 0.f;

    float4 hreg[4];   // 32 rows x 16 float4-cols, 4 per thread
    float4 wreg[8];   // 64 rows x 16 float4-cols, 8 per thread

    // --- prologue: stage chunk 0
#pragma unroll
    for (int p = 0; p < 4; ++p) {
        const int c = tid + p * 128, r = c >> 4, q = c & 15;
        hreg[p] = *reinterpret_cast<const float4*>(&hidden[(tokBase + r) * HDIM + q * 4]);
    }
#pragma unroll
    for (int p = 0; p < 8; ++p) {
        const int c = tid + p * 128, r = c >> 4, q = c & 15;
        wreg[p] = *reinterpret_cast<const float4*>(&wgate[(size_t)r * HDIM + q * 4]);
    }
#pragma unroll
    for (int p = 0; p < 4; ++p) {
        const int c = tid + p * 128, r = c >> 4, q = c & 15;
        *reinterpret_cast<float4*>(&Hs[r][q * 4]) = hreg[p];
    }
#pragma unroll
    for (int p = 0; p < 8; ++p) {
        const int c = tid + p * 128, r = c >> 4, q = c & 15;
        *reinterpret_cast<float4*>(&Wt[r][q * 4]) = wreg[p];
    }
    __syncthreads();

    for (int k0 = 0; k0 < HDIM; k0 += 64) {
        const bool more = (k0 + 64) < HDIM;
        // issue next chunk's global loads BEFORE compute (latency hides)
        if (more) {
            const int kn = k0 + 64;
#pragma unroll
            for (int p = 0; p < 4; ++p) {
                const int c = tid + p * 128, r = c >> 4, q = c & 15;
                hreg[p] = *reinterpret_cast<const float4*>(&hidden[(tokBase + r) * HDIM + kn + q * 4]);
            }
#pragma unroll
            for (int p = 0; p < 8; ++p) {
                const int c = tid + p * 128, r = c >> 4, q = c & 15;
                wreg[p] = *reinterpret_cast<const float4*>(&wgate[(size_t)r * HDIM + kn + q * 4]);
            }
        }

        // compute current chunk from LDS
#pragma unroll
        for (int kk = 0; kk < 64; kk += 4) {
            float4 w[4], h[4];
#pragma unroll
            for (int j = 0; j < 4; ++j)
                w[j] = *reinterpret_cast<const float4*>(&Wt[eg + 16 * j][kk]);
#pragma unroll
            for (int t = 0; t < 4; ++t)
                h[t] = *reinterpret_cast<const float4*>(&Hs[t * 8 + tg][kk]);
#pragma unroll
            for (int t = 0; t < 4; ++t)
#pragma unroll
                for (int j = 0; j < 4; ++j) {
                    acc[t][j] += h[t].x * w[j].x;
                    acc[t][j] += h[t].y * w[j].y;
                    acc[t][j] += h[t].z * w[j].z;
                    acc[t][j] += h[t].w * w[j].w;
                }
        }
        __syncthreads();
        if (more) {
#pragma unroll
            for (int p = 0; p < 4; ++p) {
                const int c = tid + p * 128, r = c >> 4, q = c & 15;
                *reinterpret_cast<float4*>(&Hs[r][q * 4]) = hreg[p];
            }
#pragma unroll
            for (int p = 0; p < 8; ++p) {
                const int c = tid + p * 128, r = c >> 4, q = c & 15;
                *reinterpret_cast<float4*>(&Wt[r][q * 4]) = wreg[p];
            }
            __syncthreads();
        }
    }

#pragma unroll
    for (int t = 0; t < 4; ++t)
#pragma unroll
        for (int j = 0; j < 4; ++j)
            logits[(tokBase + t * 8 + tg) * NEXP + eg + 16 * j] = acc[t][j];
}

// ---------------- Kernel B: per-token top-9 scan, flag near-ties ---------
__global__ __launch_bounds__(256) void gate_topk_flag(
    const float* __restrict__ logits,
    float* __restrict__ selw,
    float* __restrict__ selidx,
    int* __restrict__ flag,
    int T)
{
    const int t = blockIdx.x * blockDim.x + threadIdx.x;
    if (t >= T) return;

    float v[NEXP];
    const float4* row = reinterpret_cast<const float4*>(&logits[(size_t)t * NEXP]);
#pragma unroll
    for (int i = 0; i < NEXP / 4; ++i) {
        const float4 q = row[i];
        v[4 * i + 0] = q.x;
        v[4 * i + 1] = q.y;
        v[4 * i + 2] = q.z;
        v[4 * i + 3] = q.w;
    }

    float bv[NSCAN];
    int   bidx[NSCAN];
    unsigned long long used = 0ull;
#pragma unroll
    for (int k = 0; k < NSCAN; ++k) {
        float best = -INFINITY;
        int   bi   = 0;
#pragma unroll
        for (int i = 0; i < NEXP; ++i) {
            const bool avail = ((used >> i) & 1ull) == 0ull;
            if (avail && v[i] > best) { best = v[i]; bi = i; }
        }
        bv[k]   = best;
        bidx[k] = bi;
        used |= (1ull << bi);
    }

    // min adjacent gap over ranks 1..9 — any near-tie can reorder indices
    float ming = bv[0] - bv[1];
#pragma unroll
    for (int k = 1; k < NSCAN - 1; ++k) {
        const float g = bv[k] - bv[k + 1];
        ming = fminf(ming, g);
    }
    flag[t] = (ming < TAU) ? 1 : 0;

    const float m = bv[0];
    float ek[TOPK];
    float s = 0.f;
#pragma unroll
    for (int k = 0; k < TOPK; ++k) {
        ek[k] = expf(bv[k] - m);
        s += ek[k];
    }
    const float inv = 1.0f / s;
#pragma unroll
    for (int k = 0; k < TOPK; ++k) {
        selw[(size_t)t * TOPK + k]   = ek[k] * inv;
        selidx[(size_t)t * TOPK + k] = (float)bidx[k];
    }
}

// ---------------- Kernel C: fp64 re-dot + exact top-8 for flagged tokens -
// One wave per flagged token; lane = expert.
__global__ __launch_bounds__(256) void gate_fixup_f64(
    const float* __restrict__ hidden,
    const float* __restrict__ wgate,
    const int* __restrict__ flag,
    float* __restrict__ selw,
    float* __restrict__ selidx,
    int T)
{
    const int lane   = threadIdx.x & 63;
    const int waveId = (blockIdx.x * blockDim.x + threadIdx.x) >> 6;
    const int nWaves = (gridDim.x * blockDim.x) >> 6;

    for (int t = waveId; t < T; t += nWaves) {
        if (!flag[t]) continue;

        const float* hrow = &hidden[(size_t)t * HDIM];
        const float* wrow = &wgate[(size_t)lane * HDIM];
        double acc = 0.0;
#pragma unroll 4
        for (int k = 0; k < HDIM; k += 4) {
            const float4 h4 = *reinterpret_cast<const float4*>(&hrow[k]); // broadcast
            const float4 w4 = *reinterpret_cast<const float4*>(&wrow[k]);
            acc += (double)h4.x * (double)w4.x;
            acc += (double)h4.y * (double)w4.y;
            acc += (double)h4.z * (double)w4.z;
            acc += (double)h4.w * (double)w4.w;
        }

        double v  = acc;
        int    id = lane;
        double bv[TOPK];
        int    bidx[TOPK];
#pragma unroll
        for (int p = 0; p < TOPK; ++p) {
            double mv = v;
            int    mi = id;
#pragma unroll
            for (int off = 32; off >= 1; off >>= 1) {
                const double ov = __shfl_xor(mv, off);
                const int    oi = __shfl_xor(mi, off);
                if (ov > mv || (ov == mv && oi < mi)) { mv = ov; mi = oi; }
            }
            bv[p]   = mv;   // replicated across all lanes
            bidx[p] = mi;
            if (id == mi) v = -INFINITY;  // mask winner
        }

        if (lane == 0) {
            float ek[TOPK];
            float s = 0.f;
#pragma unroll
            for (int p = 0; p < TOPK; ++p) {
                ek[p] = expf((float)(bv[p] - bv[0]));
                s += ek[p];
            }
            const float inv = 1.0f / s;
#pragma unroll
            for (int p = 0; p < TOPK; ++p) {
                selw[(size_t)t * TOPK + p]   = ek[p] * inv;
                selidx[(size_t)t * TOPK + p] = (float)bidx[p];
            }
        }
    }
}

extern "C" void kernel_launch(void* const* d_in, const int* in_sizes, int n_in,
                              void* d_out, int out_size, void* d_ws, size_t ws_size,
                              hipStream_t stream) {
    const float* hidden = (const float*)d_in[0];   // [4,4096,2048] f32
    const float* wgate  = (const float*)d_in[1];   // [64,2048] f32

    const int T = in_sizes[0] / HDIM;              // 16384 tokens

    float* out    = (float*)d_out;
    float* selw   = out;                           // T*8
    float* selidx = out + (size_t)T * TOPK;        // T*8
    float* logits = out + (size_t)2 * T * TOPK;    // T*64
    int*   flag   = (int*)d_ws;                    // T ints (64 KB)

    gate_gemm_f32<<<T / 32, 128, 0, stream>>>(hidden, wgate, logits);
    gate_topk_flag<<<(T + 255) / 256, 256, 0, stream>>>(logits, selw, selidx, flag, T);
    gate_fixup_f64<<<64, 256, 0, stream>>>(hidden, wgate, flag, selw, selidx, T);
}

// Round 3
// 201.973 us; speedup vs baseline: 2.4379x; 2.4379x over previous
//
#include <hip/hip_runtime.h>
#include <math.h>

// Qwen3 MoE gate: logits = hidden @ W_gate^T ; softmax ; top-8 ; renorm.
// Outputs (flat f32): sel_w [T*8], sel_idx-as-float [T*8], logits [T*64].
//
// R3: (A) fp32 GEMM, m97-style: global_load_lds + dbuf LDS + XOR swizzle.
//     (B) top-9 scan writes outputs, appends near-tie tokens (gap < TAU) to
//         a compacted list via atomicAdd (ws; counter memset to 0 on stream).
//     (C) fp64 re-dot + exact wave top-8, one wave per flagged token, 4
//         independent accumulators (ILP) — was the 299us latency-serial tail.

#define HDIM 2048
#define NEXP 64
#define TOPK 8
#define NSCAN 9
#define TAU  2.5e-4f

// ---------------- Kernel A: fp32 GEMM, 64 tok x 64 exp per 256-thr block --
// LDS tiles stored as flat float4[1024] (row-major [64 rows][16 float4]),
// double-buffered (64 KiB). Swizzle: float4-col c4 stored at c4, sourced
// from global col (c4 ^ (row&7)); reads apply the same XOR (involution) —
// G21: linear gload_lds dest + inverse-swizzled source + swizzled read.
// Read banks: W lanes eg=0..15 -> byte eg*256 + ((q^eg&7))*16 -> 8 bank
// groups x 2-way (free); H rows broadcast 16-way per address (free).
__global__ __launch_bounds__(256) void gate_gemm_f32(
    const float* __restrict__ hidden,   // [T, 2048]
    const float* __restrict__ wgate,    // [64, 2048]
    float* __restrict__ logits)         // [T, 64]
{
    __shared__ float4 Wt[2][1024];
    __shared__ float4 Hs[2][1024];

    const int tid = threadIdx.x;
    const int eg  = tid & 15;    // expert base; experts eg+16j
    const int tg  = tid >> 4;    // token base;  tokens  tg+16t
    const size_t tokBase = (size_t)blockIdx.x * 64;

    float acc[4][4];             // [t][j]
#pragma unroll
    for (int t = 0; t < 4; ++t)
#pragma unroll
        for (int j = 0; j < 4; ++j) acc[t][j] = 0.f;

    auto stage = [&](int b, int k0) {
#pragma unroll
        for (int p = 0; p < 4; ++p) {
            const int c  = p * 256 + tid;   // float4 index 0..1023
            const int r  = c >> 4;          // row 0..63
            const int c4 = c & 15;
            const int sc = c4 ^ (r & 7);    // inverse-swizzled source col
            const float* gH = &hidden[(tokBase + r) * HDIM + k0 + sc * 4];
            const float* gW = &wgate[(size_t)r * HDIM + k0 + sc * 4];
            __builtin_amdgcn_global_load_lds(
                (const __attribute__((address_space(1))) void*)gH,
                (__attribute__((address_space(3))) void*)&Hs[b][c], 16, 0, 0);
            __builtin_amdgcn_global_load_lds(
                (const __attribute__((address_space(1))) void*)gW,
                (__attribute__((address_space(3))) void*)&Wt[b][c], 16, 0, 0);
        }
    };

    stage(0, 0);
    __syncthreads();               // compiler drains vmcnt before barrier

    int buf = 0;
    for (int k0 = 0; k0 < HDIM; k0 += 64) {
        if (k0 + 64 < HDIM) stage(buf ^ 1, k0 + 64);  // async, flies under FMA

        const int swW = eg & 7;
        const int swH = tg & 7;
#pragma unroll
        for (int q = 0; q < 16; ++q) {
            float4 w[4], h[4];
#pragma unroll
            for (int j = 0; j < 4; ++j)
                w[j] = Wt[buf][(eg + 16 * j) * 16 + (q ^ swW)];
#pragma unroll
            for (int t = 0; t < 4; ++t)
                h[t] = Hs[buf][(tg + 16 * t) * 16 + (q ^ swH)];
#pragma unroll
            for (int t = 0; t < 4; ++t)
#pragma unroll
                for (int j = 0; j < 4; ++j) {
                    acc[t][j] += h[t].x * w[j].x;
                    acc[t][j] += h[t].y * w[j].y;
                    acc[t][j] += h[t].z * w[j].z;
                    acc[t][j] += h[t].w * w[j].w;
                }
        }
        __syncthreads();           // drains the buf^1 loads + protects reuse
        buf ^= 1;
    }

#pragma unroll
    for (int t = 0; t < 4; ++t)
#pragma unroll
        for (int j = 0; j < 4; ++j)
            logits[(tokBase + tg + 16 * t) * NEXP + eg + 16 * j] = acc[t][j];
}

// ---------------- Kernel B: top-9 scan + outputs + flagged-list append ----
__global__ __launch_bounds__(64) void gate_topk_flag(
    const float* __restrict__ logits,
    float* __restrict__ selw,
    float* __restrict__ selidx,
    int* __restrict__ cnt,         // ws+0, zeroed via hipMemsetAsync
    int* __restrict__ list,        // ws+256B
    int T)
{
    const int t = blockIdx.x * 64 + threadIdx.x;
    if (t >= T) return;

    float v[NEXP];
    const float4* row = reinterpret_cast<const float4*>(&logits[(size_t)t * NEXP]);
#pragma unroll
    for (int i = 0; i < NEXP / 4; ++i) {
        const float4 q = row[i];
        v[4 * i + 0] = q.x;
        v[4 * i + 1] = q.y;
        v[4 * i + 2] = q.z;
        v[4 * i + 3] = q.w;
    }

    float bv[NSCAN];
    int   bidx[NSCAN];
    unsigned long long used = 0ull;
#pragma unroll
    for (int k = 0; k < NSCAN; ++k) {
        float best = -INFINITY;
        int   bi   = 0;
#pragma unroll
        for (int i = 0; i < NEXP; ++i) {
            const bool avail = ((used >> i) & 1ull) == 0ull;
            if (avail && v[i] > best) { best = v[i]; bi = i; }
        }
        bv[k]   = best;
        bidx[k] = bi;
        used |= (1ull << bi);
    }

    float ming = bv[0] - bv[1];
#pragma unroll
    for (int k = 1; k < NSCAN - 1; ++k) ming = fminf(ming, bv[k] - bv[k + 1]);
    if (ming < TAU) {
        const int pos = atomicAdd(cnt, 1);   // order-nondeterministic; results per-token
        list[pos] = t;
    }

    const float m = bv[0];
    float ek[TOPK];
    float s = 0.f;
#pragma unroll
    for (int k = 0; k < TOPK; ++k) { ek[k] = expf(bv[k] - m); s += ek[k]; }
    const float inv = 1.0f / s;
#pragma unroll
    for (int k = 0; k < TOPK; ++k) {
        selw[(size_t)t * TOPK + k]   = ek[k] * inv;
        selidx[(size_t)t * TOPK + k] = (float)bidx[k];
    }
}

// ---------------- Kernel C: fp64 re-dot + exact top-8, 1 wave/flagged tok -
__global__ __launch_bounds__(256) void gate_fixup_f64(
    const float* __restrict__ hidden,
    const float* __restrict__ wgate,
    const int* __restrict__ cnt,
    const int* __restrict__ list,
    float* __restrict__ selw,
    float* __restrict__ selidx)
{
    const int lane   = threadIdx.x & 63;
    const int waveId = (blockIdx.x * blockDim.x + threadIdx.x) >> 6;
    const int nWaves = (gridDim.x * blockDim.x) >> 6;
    const int n      = *cnt;

    for (int i = waveId; i < n; i += nWaves) {
        const int t = list[i];
        const float* hrow = &hidden[(size_t)t * HDIM];
        const float* wrow = &wgate[(size_t)lane * HDIM];

        // 4 independent fp64 accumulators; 16 loads in flight per 2 iters.
        double a0 = 0.0, a1 = 0.0, a2 = 0.0, a3 = 0.0;
#pragma unroll 2
        for (int k = 0; k < HDIM; k += 16) {
            const float4 h0 = *reinterpret_cast<const float4*>(&hrow[k +  0]);
            const float4 h1 = *reinterpret_cast<const float4*>(&hrow[k +  4]);
            const float4 h2 = *reinterpret_cast<const float4*>(&hrow[k +  8]);
            const float4 h3 = *reinterpret_cast<const float4*>(&hrow[k + 12]);
            const float4 w0 = *reinterpret_cast<const float4*>(&wrow[k +  0]);
            const float4 w1 = *reinterpret_cast<const float4*>(&wrow[k +  4]);
            const float4 w2 = *reinterpret_cast<const float4*>(&wrow[k +  8]);
            const float4 w3 = *reinterpret_cast<const float4*>(&wrow[k + 12]);
            a0 += (double)h0.x * w0.x + (double)h0.y * w0.y
                + (double)h0.z * w0.z + (double)h0.w * w0.w;
            a1 += (double)h1.x * w1.x + (double)h1.y * w1.y
                + (double)h1.z * w1.z + (double)h1.w * w1.w;
            a2 += (double)h2.x * w2.x + (double)h2.y * w2.y
                + (double)h2.z * w2.z + (double)h2.w * w2.w;
            a3 += (double)h3.x * w3.x + (double)h3.y * w3.y
                + (double)h3.z * w3.z + (double)h3.w * w3.w;
        }
        double v = (a0 + a1) + (a2 + a3);
        int   id = lane;

        double bv[TOPK];
        int    bidx[TOPK];
#pragma unroll
        for (int p = 0; p < TOPK; ++p) {
            double mv = v;
            int    mi = id;
#pragma unroll
            for (int off = 32; off >= 1; off >>= 1) {
                const double ov = __shfl_xor(mv, off);
                const int    oi = __shfl_xor(mi, off);
                if (ov > mv || (ov == mv && oi < mi)) { mv = ov; mi = oi; }
            }
            bv[p]   = mv;
            bidx[p] = mi;
            if (id == mi) v = -INFINITY;
        }

        if (lane == 0) {
            float ek[TOPK];
            float s = 0.f;
#pragma unroll
            for (int p = 0; p < TOPK; ++p) {
                ek[p] = expf((float)(bv[p] - bv[0]));
                s += ek[p];
            }
            const float inv = 1.0f / s;
#pragma unroll
            for (int p = 0; p < TOPK; ++p) {
                selw[(size_t)t * TOPK + p]   = ek[p] * inv;
                selidx[(size_t)t * TOPK + p] = (float)bidx[p];
            }
        }
    }
}

extern "C" void kernel_launch(void* const* d_in, const int* in_sizes, int n_in,
                              void* d_out, int out_size, void* d_ws, size_t ws_size,
                              hipStream_t stream) {
    const float* hidden = (const float*)d_in[0];   // [4,4096,2048] f32
    const float* wgate  = (const float*)d_in[1];   // [64,2048] f32

    const int T = in_sizes[0] / HDIM;              // 16384 tokens

    float* out    = (float*)d_out;
    float* selw   = out;                           // T*8
    float* selidx = out + (size_t)T * TOPK;        // T*8
    float* logits = out + (size_t)2 * T * TOPK;    // T*64

    int* cnt  = (int*)d_ws;                        // 1 int (zeroed below)
    int* list = (int*)d_ws + 64;                   // up to T ints

    hipMemsetAsync(d_ws, 0, 256, stream);          // graph-capturable

    gate_gemm_f32<<<T / 64, 256, 0, stream>>>(hidden, wgate, logits);
    gate_topk_flag<<<T / 64, 64, 0, stream>>>(logits, selw, selidx, cnt, list, T);
    gate_fixup_f64<<<256, 256, 0, stream>>>(hidden, wgate, cnt, list, selw, selidx);
}